// Round 6
// baseline (200.776 us; speedup 1.0000x reference)
//
#include <hip/hip_runtime.h>
#include <math.h>

// InfoNCE, exact JAX threefry2x32 negative-sampling reproduction.
// I=4096, E=16384, D=64.
//
// R6 (from R5 @162us, VALUBusy 64%):
//  - per-wave segmented LDS lists with register-resident wave-uniform
//    counters: ballot -> mbcnt offset -> exec-masked store -> cnt += popc.
//    Removes ALL LDS atomics + shuffle broadcasts from the hot loop.
//  - 8 elements/thread/iter (2x dwordx4 per row), threefry in two 4-eval
//    straight-line groups; adj compressed to predicate bitmasks.
//  - __launch_bounds__(256,8) pins <=64 VGPR (8 waves/SIMD).
//  - phase 2: compact 4 segments then rank/dots/loss as before.

constexpr int D      = 64;
constexpr int POS_W  = 40;    // per-wave pos seg: Binom(4096,.002) mean 8.2
constexpr int CAND_W = 64;    // per-wave cand seg: Binom(4096,1/256) mean 16
constexpr int PTOT   = 4 * POS_W;    // 160
constexpr int CTOT   = 4 * CAND_W;   // 256
constexpr int SELCAP = 256;

typedef int int4v __attribute__((ext_vector_type(4)));

// JAX threefry2x32, key = (0, 42) from jax.random.key(42).
__device__ __forceinline__ void threefry2x32(unsigned x0, unsigned x1,
                                             unsigned& o0, unsigned& o1) {
  const unsigned ks0 = 0u;
  const unsigned ks1 = 42u;
  const unsigned ks2 = 0x1BD11BDAu ^ 0u ^ 42u;
  x0 += ks0; x1 += ks1;
#define TF_R(r) { x0 += x1; x1 = (x1 << (r)) | (x1 >> (32 - (r))); x1 ^= x0; }
  TF_R(13) TF_R(15) TF_R(26) TF_R(6)
  x0 += ks1; x1 += ks2 + 1u;
  TF_R(17) TF_R(29) TF_R(16) TF_R(24)
  x0 += ks2; x1 += ks0 + 2u;
  TF_R(13) TF_R(15) TF_R(26) TF_R(6)
  x0 += ks0; x1 += ks1 + 3u;
  TF_R(17) TF_R(29) TF_R(16) TF_R(24)
  x0 += ks1; x1 += ks2 + 4u;
  TF_R(13) TF_R(15) TF_R(26) TF_R(6)
  x0 += ks2; x1 += ks0 + 5u;
#undef TF_R
  o0 = x0; o1 = x1;
}

// count of set mask bits strictly below my lane
__device__ __forceinline__ int lane_prior(unsigned long long m) {
  return (int)__builtin_amdgcn_mbcnt_hi(
      (unsigned)(m >> 32), __builtin_amdgcn_mbcnt_lo((unsigned)m, 0u));
}

// Atomic-free per-wave append: cntvar is a wave-uniform register counter.
#define APPEND1(pred, val, cntvar, seg, cap)                        \
  do {                                                              \
    unsigned long long m_ = __ballot(pred);                         \
    if (m_) {                                                       \
      int ofs_ = cntvar + lane_prior(m_);                           \
      if ((pred) && ofs_ < (cap)) (seg)[ofs_] = (val);              \
      cntvar += (int)__popcll(m_);                                  \
    }                                                               \
  } while (0)

#define APPEND2(pred, val, key, cntvar, segi, segk, cap)            \
  do {                                                              \
    unsigned long long m_ = __ballot(pred);                         \
    if (m_) {                                                       \
      int ofs_ = cntvar + lane_prior(m_);                           \
      if ((pred) && ofs_ < (cap)) {                                 \
        (segi)[ofs_] = (val); (segk)[ofs_] = (key);                 \
      }                                                             \
      cntvar += (int)__popcll(m_);                                  \
    }                                                               \
  } while (0)

// LDS-atomic wave appends (fallback path only)
__device__ __forceinline__ void wave_append(bool pred, int e,
                                            int* cnt, int* list, int cap) {
  unsigned long long m = __ballot(pred);
  if (m) {
    const int lane = threadIdx.x & 63;
    const int leader = __builtin_ctzll(m);
    int base = 0;
    if (lane == leader) base = atomicAdd(cnt, (int)__popcll(m));
    base = __shfl(base, leader, 64);
    if (pred) {
      int s = base + lane_prior(m);
      if (s < cap) list[s] = e;
    }
  }
}
__device__ __forceinline__ void wave_append2a(bool pred, int e, unsigned key,
                                              int* cnt, int* li, unsigned* lk,
                                              int cap) {
  unsigned long long m = __ballot(pred);
  if (m) {
    const int lane = threadIdx.x & 63;
    const int leader = __builtin_ctzll(m);
    int base = 0;
    if (lane == leader) base = atomicAdd(cnt, (int)__popcll(m));
    base = __shfl(base, leader, 64);
    if (pred) {
      int s = base + lane_prior(m);
      if (s < cap) { li[s] = e; lk[s] = key; }
    }
  }
}

__device__ __forceinline__ float dot_sim(const float* __restrict__ ent, int e,
                                         const float* itemn) {
  const float4* er = (const float4*)(ent + ((size_t)e << 6));
  float dot = 0.f, ss = 0.f;
#pragma unroll
  for (int q = 0; q < 16; ++q) {
    float4 f = er[q];
    dot += itemn[4 * q + 0] * f.x + itemn[4 * q + 1] * f.y +
           itemn[4 * q + 2] * f.z + itemn[4 * q + 3] * f.w;
    ss += f.x * f.x + f.y * f.y + f.z * f.z + f.w * f.w;
  }
  return dot * (1.0f / sqrtf(ss));
}

__device__ __forceinline__ float block_max(float v, float* wred, int t) {
#pragma unroll
  for (int off = 32; off; off >>= 1) v = fmaxf(v, __shfl_xor(v, off, 64));
  __syncthreads();
  if ((t & 63) == 0) wred[t >> 6] = v;
  __syncthreads();
  return fmaxf(fmaxf(wred[0], wred[1]), fmaxf(wred[2], wred[3]));
}
__device__ __forceinline__ float block_sum(float v, float* wred, int t) {
#pragma unroll
  for (int off = 32; off; off >>= 1) v += __shfl_xor(v, off, 64);
  __syncthreads();
  if ((t & 63) == 0) wred[t >> 6] = v;
  __syncthreads();
  return wred[0] + wred[1] + wred[2] + wred[3];
}

// One block per row pair (iA, iA+I/2): element j of row iA is out0 of
// threefry(j_glob, j_glob+2^25); row iB's element j is out1 of the SAME eval.
template <bool WSOUT>
__global__ __launch_bounds__(256, 8) void infonce_mono(
    const float* __restrict__ item, const float* __restrict__ ent,
    const int* __restrict__ adj, int I, int E,
    float* __restrict__ loss, int* __restrict__ cnt,
    double* __restrict__ accum, int* __restrict__ paircnt) {
  const int t = threadIdx.x;
  const int wv = t >> 6;
  const int halfI = I >> 1;
  const int iA = blockIdx.x;
  const int iB = iA + halfI;
  const unsigned HALF = (unsigned)halfI * (unsigned)E;  // 2^25
  const unsigned baseA = (unsigned)iA * (unsigned)E;

  __shared__ int s_pos[2][4][POS_W];
  __shared__ int s_ci[2][4][CAND_W];
  __shared__ unsigned s_ck[2][4][CAND_W];
  __shared__ int s_npw[2][4], s_ncw[2][4];
  __shared__ int s_posc[PTOT];
  __shared__ int s_cci[CTOT];
  __shared__ unsigned s_cck[CTOT];
  __shared__ int s_sel[SELCAP];
  __shared__ int s_hist[256];
  __shared__ float s_itemn[D];
  __shared__ float s_wred[4];
  __shared__ int s_nsel, s_bbin, s_cbef, s_fnc;
  __shared__ float s_scale;

  // ---- Phase 1: fused adj stream + threefry + atomic-free appends ----
  int* segPA = s_pos[0][wv];
  int* segPB = s_pos[1][wv];
  int* segCiA = s_ci[0][wv];
  int* segCiB = s_ci[1][wv];
  unsigned* segCkA = s_ck[0][wv];
  unsigned* segCkB = s_ck[1][wv];
  int npA = 0, npB = 0, ncA = 0, ncB = 0;

  const int* adjA = adj + (size_t)iA * E;
  const int* adjB = adj + (size_t)iB * E;
  const int niter = E >> 11;  // 2048 elements per block-iteration
  for (int i = 0; i < niter; ++i) {
    const int e0 = (i << 11) + t * 8;
    const int4v* pa4 = (const int4v*)(adjA + e0);
    const int4v* pb4 = (const int4v*)(adjB + e0);
    int4v a0 = __builtin_nontemporal_load(pa4);
    int4v a1 = __builtin_nontemporal_load(pa4 + 1);
    int4v b0 = __builtin_nontemporal_load(pb4);
    int4v b1 = __builtin_nontemporal_load(pb4 + 1);
    // compress to predicate masks (frees the vectors)
    unsigned pam = 0, pbm = 0;
    {
      int av[8] = {a0.x, a0.y, a0.z, a0.w, a1.x, a1.y, a1.z, a1.w};
      int bv[8] = {b0.x, b0.y, b0.z, b0.w, b1.x, b1.y, b1.z, b1.w};
#pragma unroll
      for (int c = 0; c < 8; ++c) {
        pam |= (av[c] > 0 ? 1u : 0u) << c;
        pbm |= (bv[c] > 0 ? 1u : 0u) << c;
      }
    }
#pragma unroll
    for (int h = 0; h < 2; ++h) {
      unsigned o0[4], o1[4];
#pragma unroll
      for (int c = 0; c < 4; ++c) {
        const unsigned x = baseA + (unsigned)(e0 + 4 * h + c);
        threefry2x32(x, x + HALF, o0[c], o1[c]);
      }
#pragma unroll
      for (int c = 0; c < 4; ++c) {
        const int e = e0 + 4 * h + c;
        const bool pa = (pam >> (4 * h + c)) & 1u;
        const bool pb = (pbm >> (4 * h + c)) & 1u;
        APPEND1(pa, e, npA, segPA, POS_W);
        APPEND1(pb, e, npB, segPB, POS_W);
        APPEND2(!pa && o0[c] < (1u << 24), e, o0[c] >> 9,
                ncA, segCiA, segCkA, CAND_W);
        APPEND2(!pb && o1[c] < (1u << 24), e, o1[c] >> 9,
                ncB, segCiB, segCkB, CAND_W);
      }
    }
  }
  if ((t & 63) == 0) {  // counters are wave-uniform
    s_npw[0][wv] = npA; s_npw[1][wv] = npB;
    s_ncw[0][wv] = ncA; s_ncw[1][wv] = ncB;
  }
  __syncthreads();

  // ---- Phase 2: per-row compact + rank + dots + loss ----
  for (int r2 = 0; r2 < 2; ++r2) {
    const int row = r2 ? iB : iA;
    const int np0 = s_npw[r2][0], np1 = s_npw[r2][1];
    const int np2 = s_npw[r2][2], np3 = s_npw[r2][3];
    const int nc0 = s_ncw[r2][0], nc1 = s_ncw[r2][1];
    const int nc2 = s_ncw[r2][2], nc3 = s_ncw[r2][3];
    const int npos = np0 + np1 + np2 + np3;
    const int nc = nc0 + nc1 + nc2 + nc3;
    const int k = min(npos, E - npos);  // NEG_RATIO = 1.0
    const bool valid = (npos > 0) && (k > 0);  // block-uniform
    bool fallback =
        (np0 > POS_W) || (np1 > POS_W) || (np2 > POS_W) || (np3 > POS_W) ||
        (nc0 > CAND_W) || (nc1 > CAND_W) || (nc2 > CAND_W) || (nc3 > CAND_W) ||
        (nc < k);
    float rowloss = 0.f;
    if (valid) {
      if (t == 0) s_nsel = 0;
      if (!fallback) {
        // compact the 4 segments (each wave copies its own)
        const int lane = t & 63;
        const int pofs = (wv > 0 ? np0 : 0) + (wv > 1 ? np1 : 0) + (wv > 2 ? np2 : 0);
        const int cofs = (wv > 0 ? nc0 : 0) + (wv > 1 ? nc1 : 0) + (wv > 2 ? nc2 : 0);
        const int myPn = s_npw[r2][wv], myCn = s_ncw[r2][wv];
        for (int i = lane; i < myPn; i += 64) s_posc[pofs + i] = s_pos[r2][wv][i];
        for (int i = lane; i < myCn; i += 64) {
          s_cci[cofs + i] = s_ci[r2][wv][i];
          s_cck[cofs + i] = s_ck[r2][wv][i];
        }
      }
      __syncthreads();

      int ncand = nc, rneed = k;
      if (fallback) {
        // ---- rare exact fallback: full row rescan, 256-bin histogram ----
        s_hist[t] = 0;
        if (t == 0) s_fnc = 0;
        __syncthreads();
        const int* adjR = adj + (size_t)row * E;
        for (int e = t; e < E; e += 256) {
          if (adjR[e] > 0) continue;
          unsigned o0, o1;
          threefry2x32(baseA + (unsigned)e, baseA + (unsigned)e + HALF, o0, o1);
          atomicAdd(&s_hist[(r2 ? o1 : o0) >> 24], 1);
        }
        __syncthreads();
        if (t == 0) {
          int cum = 0, b = 0;
          while (b < 255 && cum + s_hist[b] < k) { cum += s_hist[b]; ++b; }
          s_bbin = b; s_cbef = cum;
        }
        __syncthreads();
        const int b = s_bbin;
        for (int e = t; e < E; e += 256) {
          bool neg = (adjR[e] <= 0);
          unsigned o0, o1, bits = 0xFFFFFFFFu;
          if (neg) {
            threefry2x32(baseA + (unsigned)e, baseA + (unsigned)e + HALF, o0, o1);
            bits = r2 ? o1 : o0;
          }
          int b8 = (int)(bits >> 24);
          wave_append(neg && b8 < b, e, &s_nsel, s_sel, SELCAP);
          wave_append2a(neg && b8 == b, e, bits >> 9, &s_fnc, s_cci, s_cck, CTOT);
        }
        __syncthreads();
        ncand = min(s_fnc, CTOT);
        rneed = k - s_cbef;
      }

      // exact rank among candidates, stable tie-break (key, idx)
      for (int i = t; i < ncand; i += 256) {
        const unsigned mk = s_cck[i];
        const int mi = s_cci[i];
        int rank = 0;
        for (int c = 0; c < ncand; ++c) {
          const unsigned ck = s_cck[c];
          const int ci = s_cci[c];
          rank += (ck < mk || (ck == mk && ci < mi)) ? 1 : 0;
        }
        if (rank < rneed) {
          int s = atomicAdd(&s_nsel, 1);
          if (s < SELCAP) s_sel[s] = mi;
        }
      }

      // item row scale = 1/||item|| / T
      float iv = 0.f;
      if (t < D) iv = item[(size_t)row * D + t];
      if (t < 64) {
        float ss = iv * iv;
#pragma unroll
        for (int off = 32; off; off >>= 1) ss += __shfl_xor(ss, off, 64);
        if (t == 0) s_scale = (1.0f / sqrtf(ss)) * (1.0f / 0.07f);
      }
      __syncthreads();  // also closes the rank-append section
      if (t < D) s_itemn[t] = iv * s_scale;
      __syncthreads();
      const int nsel = min(s_nsel, SELCAP);  // == k

      float myv = (t < nsel) ? dot_sim(ent, s_sel[t], s_itemn) : -INFINITY;
      const float m = block_max(myv, s_wred, t);
      float v2 = (t < nsel) ? expf(myv - m) : 0.f;
      const float S = block_sum(v2, s_wred, t);

      float lp = 0.f;
      if (!fallback) {
        if (t < npos) {  // npos <= PTOT = 160 here
          float sp = dot_sim(ent, s_posc[t], s_itemn);
          float pm = fmaxf(sp, m);
          lp = logf(expf(sp - pm) + S * expf(m - pm)) + pm - sp;
        }
      } else {
        const int* adjR = adj + (size_t)row * E;
        for (int e = t; e < E; e += 256) {
          if (adjR[e] > 0) {
            float sp = dot_sim(ent, e, s_itemn);
            float pm = fmaxf(sp, m);
            lp += logf(expf(sp - pm) + S * expf(m - pm)) + pm - sp;
          }
        }
      }
      rowloss = block_sum(lp, s_wred, t);
    }
    if (WSOUT) {
      if (t == 0) { loss[row] = valid ? rowloss : 0.f; cnt[row] = valid ? npos : 0; }
    } else {
      if (valid && t == 0) {
        atomicAdd(accum, (double)rowloss);
        atomicAdd(paircnt, npos);
      }
    }
    __syncthreads();
  }
}

// Deterministic single-block tree reduction: out = sum(loss)/sum(cnt).
__global__ __launch_bounds__(256) void reduce_out(
    const float* __restrict__ loss, const int* __restrict__ cnt, int I,
    float* __restrict__ out) {
  const int t = threadIdx.x;
  __shared__ double s_l[256];
  __shared__ int s_n[256];
  double l = 0.0;
  int n = 0;
  for (int i = t; i < I; i += 256) { l += (double)loss[i]; n += cnt[i]; }
  s_l[t] = l; s_n[t] = n;
  __syncthreads();
  for (int off = 128; off; off >>= 1) {
    if (t < off) { s_l[t] += s_l[t + off]; s_n[t] += s_n[t + off]; }
    __syncthreads();
  }
  if (t == 0) out[0] = (s_n[0] > 0) ? (float)(s_l[0] / (double)s_n[0]) : 0.f;
}

__global__ void infonce_init(double* accum, int* cnt) {
  if (threadIdx.x == 0 && blockIdx.x == 0) { accum[0] = 0.0; cnt[0] = 0; }
}

__global__ void infonce_final(const double* __restrict__ accum,
                              const int* __restrict__ cnt,
                              float* __restrict__ out) {
  if (threadIdx.x == 0 && blockIdx.x == 0) {
    int n = cnt[0];
    out[0] = (n > 0) ? (float)(accum[0] / (double)n) : 0.f;
  }
}

extern "C" void kernel_launch(void* const* d_in, const int* in_sizes, int n_in,
                              void* d_out, int out_size, void* d_ws, size_t ws_size,
                              hipStream_t stream) {
  const float* item = (const float*)d_in[0];
  const float* ent  = (const float*)d_in[1];
  const int*   adj  = (const int*)d_in[2];
  const int I = in_sizes[0] / D;   // 4096
  const int E = in_sizes[1] / D;   // 16384

  const size_t need = (size_t)I * 8;  // loss[I] f32 + cnt[I] i32
  if (ws_size >= need && (I % 2) == 0 && (E % 2048) == 0) {
    float* loss = (float*)d_ws;
    int*   cnt  = (int*)(loss + I);
    infonce_mono<true><<<I / 2, 256, 0, stream>>>(item, ent, adj, I, E,
                                                  loss, cnt, nullptr, nullptr);
    reduce_out<<<1, 256, 0, stream>>>(loss, cnt, I, (float*)d_out);
  } else {
    double* accum   = (double*)d_ws;
    int*    paircnt = (int*)((char*)d_ws + 8);
    infonce_init<<<1, 64, 0, stream>>>(accum, paircnt);
    infonce_mono<false><<<I / 2, 256, 0, stream>>>(item, ent, adj, I, E,
                                                   nullptr, nullptr, accum, paircnt);
    infonce_final<<<1, 64, 0, stream>>>(accum, paircnt, (float*)d_out);
  }
}

// Round 7
// 195.939 us; speedup vs baseline: 1.0247x; 1.0247x over previous
//
#include <hip/hip_runtime.h>
#include <math.h>

// InfoNCE, exact JAX threefry2x32 negative-sampling reproduction.
// I=4096, E=16384, D=64.
//
// R7 = R6 minus the spill trigger. R6's launch_bounds(256,8) + 8-wide
// unroll spilled ~27KB/block to scratch (WRITE_SIZE 256KB->56MB, VALUBusy
// 64->41%). Keep the atomic-free per-wave segmented appends (register
// wave-uniform counters); revert to R5's 4-elem/thread loop body (proven
// 32-VGPR, no spill) and plain launch_bounds(256).

constexpr int D      = 64;
constexpr int POS_W  = 40;    // per-wave pos seg: Binom(4096,.002) mean 8.2
constexpr int CAND_W = 64;    // per-wave cand seg: Binom(4096,1/256) mean 16
constexpr int PTOT   = 4 * POS_W;    // 160
constexpr int CTOT   = 4 * CAND_W;   // 256
constexpr int SELCAP = 256;

typedef int int4v __attribute__((ext_vector_type(4)));

// JAX threefry2x32, key = (0, 42) from jax.random.key(42).
__device__ __forceinline__ void threefry2x32(unsigned x0, unsigned x1,
                                             unsigned& o0, unsigned& o1) {
  const unsigned ks0 = 0u;
  const unsigned ks1 = 42u;
  const unsigned ks2 = 0x1BD11BDAu ^ 0u ^ 42u;
  x0 += ks0; x1 += ks1;
#define TF_R(r) { x0 += x1; x1 = (x1 << (r)) | (x1 >> (32 - (r))); x1 ^= x0; }
  TF_R(13) TF_R(15) TF_R(26) TF_R(6)
  x0 += ks1; x1 += ks2 + 1u;
  TF_R(17) TF_R(29) TF_R(16) TF_R(24)
  x0 += ks2; x1 += ks0 + 2u;
  TF_R(13) TF_R(15) TF_R(26) TF_R(6)
  x0 += ks0; x1 += ks1 + 3u;
  TF_R(17) TF_R(29) TF_R(16) TF_R(24)
  x0 += ks1; x1 += ks2 + 4u;
  TF_R(13) TF_R(15) TF_R(26) TF_R(6)
  x0 += ks2; x1 += ks0 + 5u;
#undef TF_R
  o0 = x0; o1 = x1;
}

// count of set mask bits strictly below my lane
__device__ __forceinline__ int lane_prior(unsigned long long m) {
  return (int)__builtin_amdgcn_mbcnt_hi(
      (unsigned)(m >> 32), __builtin_amdgcn_mbcnt_lo((unsigned)m, 0u));
}

// Atomic-free per-wave append: cntvar is a wave-uniform register counter.
#define APPEND1(pred, val, cntvar, seg, cap)                        \
  do {                                                              \
    unsigned long long m_ = __ballot(pred);                         \
    if (m_) {                                                       \
      int ofs_ = cntvar + lane_prior(m_);                           \
      if ((pred) && ofs_ < (cap)) (seg)[ofs_] = (val);              \
      cntvar += (int)__popcll(m_);                                  \
    }                                                               \
  } while (0)

#define APPEND2(pred, val, key, cntvar, segi, segk, cap)            \
  do {                                                              \
    unsigned long long m_ = __ballot(pred);                         \
    if (m_) {                                                       \
      int ofs_ = cntvar + lane_prior(m_);                           \
      if ((pred) && ofs_ < (cap)) {                                 \
        (segi)[ofs_] = (val); (segk)[ofs_] = (key);                 \
      }                                                             \
      cntvar += (int)__popcll(m_);                                  \
    }                                                               \
  } while (0)

// LDS-atomic wave appends (fallback path only)
__device__ __forceinline__ void wave_append(bool pred, int e,
                                            int* cnt, int* list, int cap) {
  unsigned long long m = __ballot(pred);
  if (m) {
    const int lane = threadIdx.x & 63;
    const int leader = __builtin_ctzll(m);
    int base = 0;
    if (lane == leader) base = atomicAdd(cnt, (int)__popcll(m));
    base = __shfl(base, leader, 64);
    if (pred) {
      int s = base + lane_prior(m);
      if (s < cap) list[s] = e;
    }
  }
}
__device__ __forceinline__ void wave_append2a(bool pred, int e, unsigned key,
                                              int* cnt, int* li, unsigned* lk,
                                              int cap) {
  unsigned long long m = __ballot(pred);
  if (m) {
    const int lane = threadIdx.x & 63;
    const int leader = __builtin_ctzll(m);
    int base = 0;
    if (lane == leader) base = atomicAdd(cnt, (int)__popcll(m));
    base = __shfl(base, leader, 64);
    if (pred) {
      int s = base + lane_prior(m);
      if (s < cap) { li[s] = e; lk[s] = key; }
    }
  }
}

__device__ __forceinline__ float dot_sim(const float* __restrict__ ent, int e,
                                         const float* itemn) {
  const float4* er = (const float4*)(ent + ((size_t)e << 6));
  float dot = 0.f, ss = 0.f;
#pragma unroll
  for (int q = 0; q < 16; ++q) {
    float4 f = er[q];
    dot += itemn[4 * q + 0] * f.x + itemn[4 * q + 1] * f.y +
           itemn[4 * q + 2] * f.z + itemn[4 * q + 3] * f.w;
    ss += f.x * f.x + f.y * f.y + f.z * f.z + f.w * f.w;
  }
  return dot * (1.0f / sqrtf(ss));
}

__device__ __forceinline__ float block_max(float v, float* wred, int t) {
#pragma unroll
  for (int off = 32; off; off >>= 1) v = fmaxf(v, __shfl_xor(v, off, 64));
  __syncthreads();
  if ((t & 63) == 0) wred[t >> 6] = v;
  __syncthreads();
  return fmaxf(fmaxf(wred[0], wred[1]), fmaxf(wred[2], wred[3]));
}
__device__ __forceinline__ float block_sum(float v, float* wred, int t) {
#pragma unroll
  for (int off = 32; off; off >>= 1) v += __shfl_xor(v, off, 64);
  __syncthreads();
  if ((t & 63) == 0) wred[t >> 6] = v;
  __syncthreads();
  return wred[0] + wred[1] + wred[2] + wred[3];
}

// One block per row pair (iA, iA+I/2): element j of row iA is out0 of
// threefry(j_glob, j_glob+2^25); row iB's element j is out1 of the SAME eval.
template <bool WSOUT>
__global__ __launch_bounds__(256) void infonce_mono(
    const float* __restrict__ item, const float* __restrict__ ent,
    const int* __restrict__ adj, int I, int E,
    float* __restrict__ loss, int* __restrict__ cnt,
    double* __restrict__ accum, int* __restrict__ paircnt) {
  const int t = threadIdx.x;
  const int wv = t >> 6;
  const int halfI = I >> 1;
  const int iA = blockIdx.x;
  const int iB = iA + halfI;
  const unsigned HALF = (unsigned)halfI * (unsigned)E;  // 2^25
  const unsigned baseA = (unsigned)iA * (unsigned)E;

  __shared__ int s_pos[2][4][POS_W];
  __shared__ int s_ci[2][4][CAND_W];
  __shared__ unsigned s_ck[2][4][CAND_W];
  __shared__ int s_npw[2][4], s_ncw[2][4];
  __shared__ int s_posc[PTOT];
  __shared__ int s_cci[CTOT];
  __shared__ unsigned s_cck[CTOT];
  __shared__ int s_sel[SELCAP];
  __shared__ int s_hist[256];
  __shared__ float s_itemn[D];
  __shared__ float s_wred[4];
  __shared__ int s_nsel, s_bbin, s_cbef, s_fnc;
  __shared__ float s_scale;

  // ---- Phase 1: fused adj stream + threefry + atomic-free appends ----
  int* segPA = s_pos[0][wv];
  int* segPB = s_pos[1][wv];
  int* segCiA = s_ci[0][wv];
  int* segCiB = s_ci[1][wv];
  unsigned* segCkA = s_ck[0][wv];
  unsigned* segCkB = s_ck[1][wv];
  int npA = 0, npB = 0, ncA = 0, ncB = 0;

  const int nvec = E >> 2;
  const int4v* adjA = (const int4v*)(adj + (size_t)iA * E);
  const int4v* adjB = (const int4v*)(adj + (size_t)iB * E);
  for (int v = t; v < nvec; v += 256) {
    int4v a4 = __builtin_nontemporal_load(&adjA[v]);
    int4v b4 = __builtin_nontemporal_load(&adjB[v]);
    const unsigned e0 = (unsigned)v * 4u;
    unsigned o0[4], o1[4];
#pragma unroll
    for (int c = 0; c < 4; ++c) {  // straight-line: 4 independent evals
      const unsigned x = baseA + e0 + c;
      threefry2x32(x, x + HALF, o0[c], o1[c]);
    }
#pragma unroll
    for (int c = 0; c < 4; ++c) {
      const int e = (int)(e0 + c);
      const bool pa = (a4[c] > 0), pb = (b4[c] > 0);
      APPEND1(pa, e, npA, segPA, POS_W);
      APPEND1(pb, e, npB, segPB, POS_W);
      APPEND2(!pa && o0[c] < (1u << 24), e, o0[c] >> 9,
              ncA, segCiA, segCkA, CAND_W);
      APPEND2(!pb && o1[c] < (1u << 24), e, o1[c] >> 9,
              ncB, segCiB, segCkB, CAND_W);
    }
  }
  if ((t & 63) == 0) {  // counters are wave-uniform
    s_npw[0][wv] = npA; s_npw[1][wv] = npB;
    s_ncw[0][wv] = ncA; s_ncw[1][wv] = ncB;
  }
  __syncthreads();

  // ---- Phase 2: per-row compact + rank + dots + loss ----
  for (int r2 = 0; r2 < 2; ++r2) {
    const int row = r2 ? iB : iA;
    const int np0 = s_npw[r2][0], np1 = s_npw[r2][1];
    const int np2 = s_npw[r2][2], np3 = s_npw[r2][3];
    const int nc0 = s_ncw[r2][0], nc1 = s_ncw[r2][1];
    const int nc2 = s_ncw[r2][2], nc3 = s_ncw[r2][3];
    const int npos = np0 + np1 + np2 + np3;
    const int nc = nc0 + nc1 + nc2 + nc3;
    const int k = min(npos, E - npos);  // NEG_RATIO = 1.0
    const bool valid = (npos > 0) && (k > 0);  // block-uniform
    bool fallback =
        (np0 > POS_W) || (np1 > POS_W) || (np2 > POS_W) || (np3 > POS_W) ||
        (nc0 > CAND_W) || (nc1 > CAND_W) || (nc2 > CAND_W) || (nc3 > CAND_W) ||
        (nc < k);
    float rowloss = 0.f;
    if (valid) {
      if (t == 0) s_nsel = 0;
      if (!fallback) {
        // compact the 4 segments (each wave copies its own)
        const int lane = t & 63;
        const int pofs = (wv > 0 ? np0 : 0) + (wv > 1 ? np1 : 0) + (wv > 2 ? np2 : 0);
        const int cofs = (wv > 0 ? nc0 : 0) + (wv > 1 ? nc1 : 0) + (wv > 2 ? nc2 : 0);
        const int myPn = s_npw[r2][wv], myCn = s_ncw[r2][wv];
        for (int i = lane; i < myPn; i += 64) s_posc[pofs + i] = s_pos[r2][wv][i];
        for (int i = lane; i < myCn; i += 64) {
          s_cci[cofs + i] = s_ci[r2][wv][i];
          s_cck[cofs + i] = s_ck[r2][wv][i];
        }
      }
      __syncthreads();

      int ncand = nc, rneed = k;
      if (fallback) {
        // ---- rare exact fallback: full row rescan, 256-bin histogram ----
        s_hist[t] = 0;
        if (t == 0) s_fnc = 0;
        __syncthreads();
        const int* adjR = adj + (size_t)row * E;
        for (int e = t; e < E; e += 256) {
          if (adjR[e] > 0) continue;
          unsigned o0, o1;
          threefry2x32(baseA + (unsigned)e, baseA + (unsigned)e + HALF, o0, o1);
          atomicAdd(&s_hist[(r2 ? o1 : o0) >> 24], 1);
        }
        __syncthreads();
        if (t == 0) {
          int cum = 0, b = 0;
          while (b < 255 && cum + s_hist[b] < k) { cum += s_hist[b]; ++b; }
          s_bbin = b; s_cbef = cum;
        }
        __syncthreads();
        const int b = s_bbin;
        for (int e = t; e < E; e += 256) {
          bool neg = (adjR[e] <= 0);
          unsigned o0, o1, bits = 0xFFFFFFFFu;
          if (neg) {
            threefry2x32(baseA + (unsigned)e, baseA + (unsigned)e + HALF, o0, o1);
            bits = r2 ? o1 : o0;
          }
          int b8 = (int)(bits >> 24);
          wave_append(neg && b8 < b, e, &s_nsel, s_sel, SELCAP);
          wave_append2a(neg && b8 == b, e, bits >> 9, &s_fnc, s_cci, s_cck, CTOT);
        }
        __syncthreads();
        ncand = min(s_fnc, CTOT);
        rneed = k - s_cbef;
      }

      // exact rank among candidates, stable tie-break (key, idx)
      for (int i = t; i < ncand; i += 256) {
        const unsigned mk = s_cck[i];
        const int mi = s_cci[i];
        int rank = 0;
        for (int c = 0; c < ncand; ++c) {
          const unsigned ck = s_cck[c];
          const int ci = s_cci[c];
          rank += (ck < mk || (ck == mk && ci < mi)) ? 1 : 0;
        }
        if (rank < rneed) {
          int s = atomicAdd(&s_nsel, 1);
          if (s < SELCAP) s_sel[s] = mi;
        }
      }

      // item row scale = 1/||item|| / T
      float iv = 0.f;
      if (t < D) iv = item[(size_t)row * D + t];
      if (t < 64) {
        float ss = iv * iv;
#pragma unroll
        for (int off = 32; off; off >>= 1) ss += __shfl_xor(ss, off, 64);
        if (t == 0) s_scale = (1.0f / sqrtf(ss)) * (1.0f / 0.07f);
      }
      __syncthreads();  // also closes the rank-append section
      if (t < D) s_itemn[t] = iv * s_scale;
      __syncthreads();
      const int nsel = min(s_nsel, SELCAP);  // == k

      float myv = (t < nsel) ? dot_sim(ent, s_sel[t], s_itemn) : -INFINITY;
      const float m = block_max(myv, s_wred, t);
      float v2 = (t < nsel) ? expf(myv - m) : 0.f;
      const float S = block_sum(v2, s_wred, t);

      float lp = 0.f;
      if (!fallback) {
        if (t < npos) {  // npos <= PTOT = 160 here
          float sp = dot_sim(ent, s_posc[t], s_itemn);
          float pm = fmaxf(sp, m);
          lp = logf(expf(sp - pm) + S * expf(m - pm)) + pm - sp;
        }
      } else {
        const int* adjR = adj + (size_t)row * E;
        for (int e = t; e < E; e += 256) {
          if (adjR[e] > 0) {
            float sp = dot_sim(ent, e, s_itemn);
            float pm = fmaxf(sp, m);
            lp += logf(expf(sp - pm) + S * expf(m - pm)) + pm - sp;
          }
        }
      }
      rowloss = block_sum(lp, s_wred, t);
    }
    if (WSOUT) {
      if (t == 0) { loss[row] = valid ? rowloss : 0.f; cnt[row] = valid ? npos : 0; }
    } else {
      if (valid && t == 0) {
        atomicAdd(accum, (double)rowloss);
        atomicAdd(paircnt, npos);
      }
    }
    __syncthreads();
  }
}

// Deterministic single-block tree reduction: out = sum(loss)/sum(cnt).
__global__ __launch_bounds__(256) void reduce_out(
    const float* __restrict__ loss, const int* __restrict__ cnt, int I,
    float* __restrict__ out) {
  const int t = threadIdx.x;
  __shared__ double s_l[256];
  __shared__ int s_n[256];
  double l = 0.0;
  int n = 0;
  for (int i = t; i < I; i += 256) { l += (double)loss[i]; n += cnt[i]; }
  s_l[t] = l; s_n[t] = n;
  __syncthreads();
  for (int off = 128; off; off >>= 1) {
    if (t < off) { s_l[t] += s_l[t + off]; s_n[t] += s_n[t + off]; }
    __syncthreads();
  }
  if (t == 0) out[0] = (s_n[0] > 0) ? (float)(s_l[0] / (double)s_n[0]) : 0.f;
}

__global__ void infonce_init(double* accum, int* cnt) {
  if (threadIdx.x == 0 && blockIdx.x == 0) { accum[0] = 0.0; cnt[0] = 0; }
}

__global__ void infonce_final(const double* __restrict__ accum,
                              const int* __restrict__ cnt,
                              float* __restrict__ out) {
  if (threadIdx.x == 0 && blockIdx.x == 0) {
    int n = cnt[0];
    out[0] = (n > 0) ? (float)(accum[0] / (double)n) : 0.f;
  }
}

extern "C" void kernel_launch(void* const* d_in, const int* in_sizes, int n_in,
                              void* d_out, int out_size, void* d_ws, size_t ws_size,
                              hipStream_t stream) {
  const float* item = (const float*)d_in[0];
  const float* ent  = (const float*)d_in[1];
  const int*   adj  = (const int*)d_in[2];
  const int I = in_sizes[0] / D;   // 4096
  const int E = in_sizes[1] / D;   // 16384

  const size_t need = (size_t)I * 8;  // loss[I] f32 + cnt[I] i32
  if (ws_size >= need && (I % 2) == 0 && (E % 1024) == 0) {
    float* loss = (float*)d_ws;
    int*   cnt  = (int*)(loss + I);
    infonce_mono<true><<<I / 2, 256, 0, stream>>>(item, ent, adj, I, E,
                                                  loss, cnt, nullptr, nullptr);
    reduce_out<<<1, 256, 0, stream>>>(loss, cnt, I, (float*)d_out);
  } else {
    double* accum   = (double*)d_ws;
    int*    paircnt = (int*)((char*)d_ws + 8);
    infonce_init<<<1, 64, 0, stream>>>(accum, paircnt);
    infonce_mono<false><<<I / 2, 256, 0, stream>>>(item, ent, adj, I, E,
                                                   nullptr, nullptr, accum, paircnt);
    infonce_final<<<1, 64, 0, stream>>>(accum, paircnt, (float*)d_out);
  }
}

// Round 8
// 158.360 us; speedup vs baseline: 1.2678x; 1.2373x over previous
//
#include <hip/hip_runtime.h>
#include <math.h>

// InfoNCE, exact JAX threefry2x32 negative-sampling reproduction.
// I=4096, E=16384, D=64.
//
// R8 = R5 (best measured: 162us prof, VALUBusy 64%, VGPR 32) plus:
//  - software-pipelined adj loads: prefetch iter i+1's dwordx4 pair
//    before processing iter i (hides ~600-900cyc load latency under
//    ~800cyc of threefry issue; +8 VGPR, stays under the 64-VGPR
//    occupancy cliff that killed R7).
//  - readlane (1 VALU op, uniform lane idx) instead of __shfl
//    (ds_bpermute + lgkm wait) for the append leader-base broadcast.
// R6/R7 lesson: VGPR<=64 (8 waves/SIMD) beats removing LDS atomics.

constexpr int D      = 64;
constexpr int PCAP   = 96;    // num_pos ~ Binom(16384,.002): mean 33
constexpr int CCAP   = 192;   // bin-0 negs ~ Binom(16384,1/256): mean 64
constexpr int SELCAP = 128;   // k <= npos <= PCAP

typedef int int4v __attribute__((ext_vector_type(4)));

// JAX threefry2x32, key = (0, 42) from jax.random.key(42).
__device__ __forceinline__ void threefry2x32(unsigned x0, unsigned x1,
                                             unsigned& o0, unsigned& o1) {
  const unsigned ks0 = 0u;
  const unsigned ks1 = 42u;
  const unsigned ks2 = 0x1BD11BDAu ^ 0u ^ 42u;
  x0 += ks0; x1 += ks1;
#define TF_R(r) { x0 += x1; x1 = (x1 << (r)) | (x1 >> (32 - (r))); x1 ^= x0; }
  TF_R(13) TF_R(15) TF_R(26) TF_R(6)
  x0 += ks1; x1 += ks2 + 1u;
  TF_R(17) TF_R(29) TF_R(16) TF_R(24)
  x0 += ks2; x1 += ks0 + 2u;
  TF_R(13) TF_R(15) TF_R(26) TF_R(6)
  x0 += ks0; x1 += ks1 + 3u;
  TF_R(17) TF_R(29) TF_R(16) TF_R(24)
  x0 += ks1; x1 += ks2 + 4u;
  TF_R(13) TF_R(15) TF_R(26) TF_R(6)
  x0 += ks2; x1 += ks0 + 5u;
#undef TF_R
  o0 = x0; o1 = x1;
}

// count of set mask bits strictly below my lane
__device__ __forceinline__ int lane_prior(unsigned long long m) {
  return (int)__builtin_amdgcn_mbcnt_hi(
      (unsigned)(m >> 32), __builtin_amdgcn_mbcnt_lo((unsigned)m, 0u));
}

// wave-cooperative list append: one leader atomic, readlane broadcast.
// Uniform-skips entirely when no lane matches (the common case).
__device__ __forceinline__ void wave_append(bool pred, int e,
                                            int* cnt, int* list, int cap) {
  unsigned long long m = __ballot(pred);
  if (m) {
    const int lane = threadIdx.x & 63;
    const int leader = __builtin_ctzll(m);
    int base = 0;
    if (lane == leader) base = atomicAdd(cnt, (int)__popcll(m));
    base = __builtin_amdgcn_readlane(base, leader);  // uniform idx: 1 VALU op
    if (pred) {
      int s = base + lane_prior(m);
      if (s < cap) list[s] = e;
    }
  }
}

__device__ __forceinline__ void wave_append2(bool pred, int e, unsigned key,
                                             int* cnt, int* li, unsigned* lk,
                                             int cap) {
  unsigned long long m = __ballot(pred);
  if (m) {
    const int lane = threadIdx.x & 63;
    const int leader = __builtin_ctzll(m);
    int base = 0;
    if (lane == leader) base = atomicAdd(cnt, (int)__popcll(m));
    base = __builtin_amdgcn_readlane(base, leader);
    if (pred) {
      int s = base + lane_prior(m);
      if (s < cap) { li[s] = e; lk[s] = key; }
    }
  }
}

__device__ __forceinline__ float dot_sim(const float* __restrict__ ent, int e,
                                         const float* itemn) {
  const float4* er = (const float4*)(ent + ((size_t)e << 6));
  float dot = 0.f, ss = 0.f;
#pragma unroll
  for (int q = 0; q < 16; ++q) {
    float4 f = er[q];
    dot += itemn[4 * q + 0] * f.x + itemn[4 * q + 1] * f.y +
           itemn[4 * q + 2] * f.z + itemn[4 * q + 3] * f.w;
    ss += f.x * f.x + f.y * f.y + f.z * f.z + f.w * f.w;
  }
  return dot * (1.0f / sqrtf(ss));
}

__device__ __forceinline__ float block_max(float v, float* wred, int t) {
#pragma unroll
  for (int off = 32; off; off >>= 1) v = fmaxf(v, __shfl_xor(v, off, 64));
  __syncthreads();
  if ((t & 63) == 0) wred[t >> 6] = v;
  __syncthreads();
  return fmaxf(fmaxf(wred[0], wred[1]), fmaxf(wred[2], wred[3]));
}

__device__ __forceinline__ float block_sum(float v, float* wred, int t) {
#pragma unroll
  for (int off = 32; off; off >>= 1) v += __shfl_xor(v, off, 64);
  __syncthreads();
  if ((t & 63) == 0) wred[t >> 6] = v;
  __syncthreads();
  return wred[0] + wred[1] + wred[2] + wred[3];
}

// One block per row pair (iA, iA+I/2): element j of row iA is out0 of
// threefry(j_glob, j_glob+2^25); row iB's element j is out1 of the SAME eval.
template <bool WSOUT>
__global__ __launch_bounds__(256) void infonce_mono(
    const float* __restrict__ item, const float* __restrict__ ent,
    const int* __restrict__ adj, int I, int E,
    float* __restrict__ loss, int* __restrict__ cnt,
    double* __restrict__ accum, int* __restrict__ paircnt) {
  const int t = threadIdx.x;
  const int halfI = I >> 1;
  const int iA = blockIdx.x;
  const int iB = iA + halfI;
  const unsigned HALF = (unsigned)halfI * (unsigned)E;  // 2^25
  const unsigned baseA = (unsigned)iA * (unsigned)E;

  __shared__ int s_pos[2][PCAP];
  __shared__ int s_ci[2][CCAP];
  __shared__ unsigned s_ck[2][CCAP];
  __shared__ int s_sel[SELCAP];
  __shared__ int s_hist[256];
  __shared__ float s_itemn[D];
  __shared__ float s_wred[4];
  __shared__ int s_np[2], s_nc[2];
  __shared__ int s_nsel, s_bbin, s_cbef, s_fnc;
  __shared__ float s_scale;

  if (t < 2) { s_np[t] = 0; s_nc[t] = 0; }
  __syncthreads();

  // ---- Phase 1: adj stream (2-stage prefetch) + threefry + appends ----
  const int nvec = E >> 2;
  const int4v* adjA = (const int4v*)(adj + (size_t)iA * E);
  const int4v* adjB = (const int4v*)(adj + (size_t)iB * E);
  int4v a4 = __builtin_nontemporal_load(&adjA[t]);
  int4v b4 = __builtin_nontemporal_load(&adjB[t]);
  for (int v = t; v < nvec; v += 256) {
    // issue next iteration's loads before touching this iteration's data
    int4v an, bn;
    const int vn = v + 256;
    if (vn < nvec) {
      an = __builtin_nontemporal_load(&adjA[vn]);
      bn = __builtin_nontemporal_load(&adjB[vn]);
    }
    const unsigned e0 = (unsigned)v * 4u;
    unsigned o0[4], o1[4];
#pragma unroll
    for (int c = 0; c < 4; ++c) {  // straight-line: 4 independent evals
      const unsigned x = baseA + e0 + c;
      threefry2x32(x, x + HALF, o0[c], o1[c]);
    }
#pragma unroll
    for (int c = 0; c < 4; ++c) {
      const int e = (int)(e0 + c);
      const bool pa = (a4[c] > 0), pb = (b4[c] > 0);
      wave_append(pa, e, &s_np[0], s_pos[0], PCAP);
      wave_append(pb, e, &s_np[1], s_pos[1], PCAP);
      wave_append2(!pa && o0[c] < (1u << 24), e, o0[c] >> 9,
                   &s_nc[0], s_ci[0], s_ck[0], CCAP);
      wave_append2(!pb && o1[c] < (1u << 24), e, o1[c] >> 9,
                   &s_nc[1], s_ci[1], s_ck[1], CCAP);
    }
    a4 = an; b4 = bn;
  }
  __syncthreads();

  // ---- Phase 2: per-row selection + loss (identical to R5) ----
  for (int r2 = 0; r2 < 2; ++r2) {
    const int row = r2 ? iB : iA;
    const int npos = min(s_np[r2], PCAP);
    const int k = min(npos, E - npos);  // NEG_RATIO = 1.0
    const bool valid = (npos > 0 && k > 0);  // block-uniform
    float rowloss = 0.f;
    if (valid) {
      if (t == 0) s_nsel = 0;
      __syncthreads();
      int ncand = min(s_nc[r2], CCAP);  // all candidates are negatives
      int rneed = k;
      if (s_nc[r2] > CCAP || ncand < k) {
        // ---- rare exact fallback: full row rescan, 256-bin histogram ----
        s_hist[t] = 0;
        if (t == 0) s_fnc = 0;
        __syncthreads();
        const int* adjR = adj + (size_t)row * E;
        for (int e = t; e < E; e += 256) {
          if (adjR[e] > 0) continue;
          unsigned o0, o1;
          threefry2x32(baseA + (unsigned)e, baseA + (unsigned)e + HALF, o0, o1);
          atomicAdd(&s_hist[(r2 ? o1 : o0) >> 24], 1);
        }
        __syncthreads();
        if (t == 0) {
          int cum = 0, b = 0;
          while (b < 255 && cum + s_hist[b] < k) { cum += s_hist[b]; ++b; }
          s_bbin = b; s_cbef = cum;
        }
        __syncthreads();
        const int b = s_bbin;
        for (int e = t; e < E; e += 256) {
          bool neg = (adjR[e] <= 0);
          unsigned o0, o1, bits = 0xFFFFFFFFu;
          if (neg) {
            threefry2x32(baseA + (unsigned)e, baseA + (unsigned)e + HALF, o0, o1);
            bits = r2 ? o1 : o0;
          }
          int b8 = (int)(bits >> 24);
          wave_append(neg && b8 < b, e, &s_nsel, s_sel, SELCAP);
          wave_append2(neg && b8 == b, e, bits >> 9,
                       &s_fnc, s_ci[r2], s_ck[r2], CCAP);
        }
        __syncthreads();
        ncand = min(s_fnc, CCAP);
        rneed = k - s_cbef;
      }

      // exact rank among candidates, stable tie-break (key, idx)
      for (int i = t; i < ncand; i += 256) {
        const unsigned mk = s_ck[r2][i];
        const int mi = s_ci[r2][i];
        int rank = 0;
        for (int c = 0; c < ncand; ++c) {
          const unsigned ck = s_ck[r2][c];
          const int ci = s_ci[r2][c];
          rank += (ck < mk || (ck == mk && ci < mi)) ? 1 : 0;
        }
        if (rank < rneed) {
          int s = atomicAdd(&s_nsel, 1);
          if (s < SELCAP) s_sel[s] = mi;
        }
      }

      // item row scale = 1/||item|| / T
      float iv = 0.f;
      if (t < D) iv = item[(size_t)row * D + t];
      if (t < 64) {
        float ss = iv * iv;
#pragma unroll
        for (int off = 32; off; off >>= 1) ss += __shfl_xor(ss, off, 64);
        if (t == 0) s_scale = (1.0f / sqrtf(ss)) * (1.0f / 0.07f);
      }
      __syncthreads();  // also closes the rank-append section
      if (t < D) s_itemn[t] = iv * s_scale;
      __syncthreads();
      const int nsel = min(s_nsel, SELCAP);  // == k

      float myv = (t < nsel) ? dot_sim(ent, s_sel[t], s_itemn) : -INFINITY;
      const float m = block_max(myv, s_wred, t);
      float v2 = (t < nsel) ? expf(myv - m) : 0.f;  // register reuse, no 2nd dot
      const float S = block_sum(v2, s_wred, t);

      float lp = 0.f;
      if (t < npos) {
        float sp = dot_sim(ent, s_pos[r2][t], s_itemn);
        float pm = fmaxf(sp, m);
        lp = logf(expf(sp - pm) + S * expf(m - pm)) + pm - sp;
      }
      rowloss = block_sum(lp, s_wred, t);
    }
    if (WSOUT) {
      if (t == 0) { loss[row] = valid ? rowloss : 0.f; cnt[row] = valid ? npos : 0; }
    } else {
      if (valid && t == 0) {
        atomicAdd(accum, (double)rowloss);
        atomicAdd(paircnt, npos);
      }
    }
    __syncthreads();
  }
}

// Deterministic single-block tree reduction: out = sum(loss)/sum(cnt).
__global__ __launch_bounds__(256) void reduce_out(
    const float* __restrict__ loss, const int* __restrict__ cnt, int I,
    float* __restrict__ out) {
  const int t = threadIdx.x;
  __shared__ double s_l[256];
  __shared__ int s_n[256];
  double l = 0.0;
  int n = 0;
  for (int i = t; i < I; i += 256) { l += (double)loss[i]; n += cnt[i]; }
  s_l[t] = l; s_n[t] = n;
  __syncthreads();
  for (int off = 128; off; off >>= 1) {
    if (t < off) { s_l[t] += s_l[t + off]; s_n[t] += s_n[t + off]; }
    __syncthreads();
  }
  if (t == 0) out[0] = (s_n[0] > 0) ? (float)(s_l[0] / (double)s_n[0]) : 0.f;
}

__global__ void infonce_init(double* accum, int* cnt) {
  if (threadIdx.x == 0 && blockIdx.x == 0) { accum[0] = 0.0; cnt[0] = 0; }
}

__global__ void infonce_final(const double* __restrict__ accum,
                              const int* __restrict__ cnt,
                              float* __restrict__ out) {
  if (threadIdx.x == 0 && blockIdx.x == 0) {
    int n = cnt[0];
    out[0] = (n > 0) ? (float)(accum[0] / (double)n) : 0.f;
  }
}

extern "C" void kernel_launch(void* const* d_in, const int* in_sizes, int n_in,
                              void* d_out, int out_size, void* d_ws, size_t ws_size,
                              hipStream_t stream) {
  const float* item = (const float*)d_in[0];
  const float* ent  = (const float*)d_in[1];
  const int*   adj  = (const int*)d_in[2];
  const int I = in_sizes[0] / D;   // 4096
  const int E = in_sizes[1] / D;   // 16384

  const size_t need = (size_t)I * 8;  // loss[I] f32 + cnt[I] i32
  if (ws_size >= need && (I % 2) == 0) {
    float* loss = (float*)d_ws;
    int*   cnt  = (int*)(loss + I);
    infonce_mono<true><<<I / 2, 256, 0, stream>>>(item, ent, adj, I, E,
                                                  loss, cnt, nullptr, nullptr);
    reduce_out<<<1, 256, 0, stream>>>(loss, cnt, I, (float*)d_out);
  } else {
    double* accum   = (double*)d_ws;
    int*    paircnt = (int*)((char*)d_ws + 8);
    infonce_init<<<1, 64, 0, stream>>>(accum, paircnt);
    infonce_mono<false><<<I / 2, 256, 0, stream>>>(item, ent, adj, I, E,
                                                   nullptr, nullptr, accum, paircnt);
    infonce_final<<<1, 64, 0, stream>>>(accum, paircnt, (float*)d_out);
  }
}